// Round 22
// baseline (273.650 us; speedup 1.0000x reference)
//
#include <hip/hip_runtime.h>
#include <hip/hip_fp16.h>

// Node_Embedding: HeteroGraphConv(sum) of 4 GraphConv relations + PReLU.
// Pipeline (no global atomics in hot paths, no memsets, 6 launches):
//   k_cvt (x->fp16 + W-pack, zeroes scan counter) ; k_hist8 (single-read
//   full-range u8-packed LDS edge histograms) ; k_scan1 (chunk-prefix + coef
//   + local CSR scan; LAST block also scans chunk totals — old scan2) ;
//   k_fill3 (chunked LDS-cursor counting sort) ; k_gather (range-sorted
//   barrier-free pipelined gather) ; k_gemm (MFMA f16 + bias + PReLU).
// R21 lesson: per-pass barriers + run-table in gather were overhead (sort
// alone provides range locality); scan2 folded via completion counter.

#define NB 50000   // nodes per type
#define EB 500000  // edges per relation
#define D  128
#define NCH 98     // ceil(NB/512)
#define CAP 1024   // gather LDS edge capacity (mean 640 per 64 rows)
#define NCHK 16    // edge chunks (CSR build)
#define CH2 15625  // (EB/NCHK)/2 int2 loads per chunk
#define NRG 4      // node ranges (fill)
#define FR 12500   // nodes per range (fill)
#define NRGP 4     // gather src-range sort buckets
#define RQ 12500   // NB/NRGP

struct EdgePtrs { const int* src[4]; const int* dst[4]; };

typedef _Float16 f16x8 __attribute__((ext_vector_type(8)));
typedef float f32x4 __attribute__((ext_vector_type(4)));

__device__ inline float hlo(unsigned u) {
    return __half2float(__ushort_as_half((unsigned short)(u & 0xffffu)));
}
__device__ inline float hhi(unsigned u) {
    return __half2float(__ushort_as_half((unsigned short)(u >> 16)));
}

// x (fp32) -> fp16, float4/thread; last 32 blocks pack W into MFMA B-frags.
// Block 0 zeroes the scan completion counter.
__global__ __launch_bounds__(256) void k_cvt(const float* __restrict__ xd,
                                             const float* __restrict__ xs,
                                             unsigned short* __restrict__ xh,
                                             const float* __restrict__ W,
                                             _Float16* __restrict__ Wb,
                                             int* __restrict__ done) {
    int bx = blockIdx.x;
    if (bx == 0 && threadIdx.x == 0) *done = 0;
    if (bx < 12500) {
        int i = bx * 256 + threadIdx.x;   // float4 index, 3.2M total
        const int half = NB * D / 4;
        const float* src = (i < half) ? xd : xs;
        int j = (i < half) ? i : i - half;
        float4 v = reinterpret_cast<const float4*>(src)[j];
        ushort4 o;
        o.x = __half_as_ushort(__float2half(v.x));
        o.y = __half_as_ushort(__float2half(v.y));
        o.z = __half_as_ushort(__float2half(v.z));
        o.w = __half_as_ushort(__float2half(v.w));
        reinterpret_cast<ushort4*>(xh)[i] = o;
    } else {
        int idx = (bx - 12500) * 256 + threadIdx.x;   // 8192 total
        int t = idx >> 12, jt = (idx >> 9) & 7, ks = (idx >> 6) & 7, l = idx & 63;
        int col = jt * 16 + (l & 15);
        int kb = ks * 32 + (l >> 4) * 8;
        _Float16 h[8];
#pragma unroll
        for (int m = 0; m < 8; ++m) {
            int k = kb + m;
            int r = (k < 128) ? t : (2 + t);
            h[m] = (_Float16)W[r * D * D + (k & 127) * D + col];
        }
        *reinterpret_cast<f16x8*>(Wb + (size_t)idx * 8) = *reinterpret_cast<f16x8*>(h);
    }
}

// Full-range u8-packed LDS histogram; block (chunk, z) with z = io*4 + rel.
__global__ __launch_bounds__(256) void k_hist8(EdgePtrs ep,
                                               unsigned short* __restrict__ cnt2in,
                                               unsigned short* __restrict__ cnt2o) {
    __shared__ unsigned pk[NB / 4];   // 50 KB packed u8 counters
    const int chunk = blockIdx.x, z = blockIdx.y;
    const int rel = z & 3, io = z >> 2;
    const int* arr = io ? ep.src[rel] : ep.dst[rel];
    for (int i = threadIdx.x; i < NB / 4; i += 256) pk[i] = 0;
    __syncthreads();
    const int2* a2 = reinterpret_cast<const int2*>(arr) + (size_t)chunk * CH2;
    for (int i = threadIdx.x; i < CH2; i += 256) {
        int2 v = a2[i];
        atomicAdd(&pk[v.x >> 2], 1u << (8 * (v.x & 3)));
        atomicAdd(&pk[v.y >> 2], 1u << (8 * (v.y & 3)));
    }
    __syncthreads();
    unsigned short* outp =
        (io ? cnt2o : cnt2in) + ((size_t)(rel * NCHK + chunk)) * NB;
    for (int i = threadIdx.x; i < NB / 4; i += 256) {
        unsigned p = pk[i];
        ushort4 o4;
        o4.x = (unsigned short)(p & 0xff);
        o4.y = (unsigned short)((p >> 8) & 0xff);
        o4.z = (unsigned short)((p >> 16) & 0xff);
        o4.w = (unsigned short)(p >> 24);
        *reinterpret_cast<ushort4*>(outp + 4 * i) = o4;
    }
}

// Phase 1: per node — chunk-prefix cnt2in in place (u16), outdeg -> coef,
// per-512-node exclusive block scan (LOCAL offs). The LAST finishing block
// additionally scans the chunk totals (old scan2), via completion counter.
__global__ __launch_bounds__(512) void k_scan1(unsigned short* __restrict__ cnt2in,
                                               const unsigned short* __restrict__ cnt2o,
                                               float* __restrict__ coef,
                                               int* __restrict__ offs,
                                               int* __restrict__ chunksum,
                                               int* __restrict__ done) {
    int r = blockIdx.y, c = blockIdx.x, t = threadIdx.x;
    int node = c * 512 + t;
    int v = 0;
    if (node < NB) {
        int tin = 0;
#pragma unroll
        for (int k = 0; k < NCHK; ++k) {
            size_t idx = ((size_t)(r * NCHK + k)) * NB + node;
            int cc = cnt2in[idx];
            cnt2in[idx] = (unsigned short)tin;   // exclusive chunk prefix
            tin += cc;
        }
        v = tin;
        int tout = 0;
#pragma unroll
        for (int k = 0; k < NCHK; ++k)
            tout += cnt2o[((size_t)(r * NCHK + k)) * NB + node];
        coef[r * NB + node] = rsqrtf((float)(tout > 1 ? tout : 1));
    }
    __shared__ int sh[512];
    __shared__ int lastflag;
    sh[t] = v;
    __syncthreads();
    for (int off = 1; off < 512; off <<= 1) {
        int u = (t >= off) ? sh[t - off] : 0;
        __syncthreads();
        sh[t] += u;
        __syncthreads();
    }
    int incl = sh[t];
    if (node < NB) offs[r * (NB + 1) + node] = incl - v;  // local exclusive
    if (t == 511) chunksum[r * NCH + c] = incl;
    __threadfence();
    __syncthreads();
    if (t == 0) {
        int got = atomicAdd(done, 1);
        lastflag = (got == 4 * NCH - 1);
    }
    __syncthreads();
    if (lastflag && t < 256) {
        __threadfence();   // acquire: see all blocks' chunksum stores
        int rr = t >> 6, lane = t & 63;
        int* cs = chunksum + rr * NCH;
        int s0 = cs[lane];
        int s1 = (64 + lane < NCH) ? cs[64 + lane] : 0;
        int x = s0;
        for (int d2 = 1; d2 < 64; d2 <<= 1) {
            int u = __shfl_up(x, d2, 64); if (lane >= d2) x += u;
        }
        int tot00 = __shfl(x, 63, 64);
        int y = s1;
        for (int d2 = 1; d2 < 64; d2 <<= 1) {
            int u = __shfl_up(y, d2, 64); if (lane >= d2) y += u;
        }
        y += tot00;
        cs[lane] = x - s0;
        if (64 + lane < NCH) cs[64 + lane] = y - s1;
    }
}

// Chunked counting-sort placement: int2 (src, coef) payload. Final CSR
// position = local offs + chunksum base + chunk prefix (+ LDS rank cursor).
__global__ __launch_bounds__(256) void k_fill3(EdgePtrs ep,
                                               const unsigned short* __restrict__ cnt2in,
                                               const float* __restrict__ coef,
                                               const int* __restrict__ offs,
                                               const int* __restrict__ chunksum,
                                               int2* __restrict__ epack) {
    __shared__ int cur[FR];           // 50 KB
    const int chunk = blockIdx.x, range = blockIdx.y, rel = blockIdx.z;
    const int lo = range * FR;
    const unsigned short* pre = cnt2in + ((size_t)(rel * NCHK + chunk)) * NB;
    for (int i = threadIdx.x; i < FR; i += 256) {
        int node = lo + i;
        cur[i] = offs[rel * (NB + 1) + node]
               + chunksum[rel * NCH + (node >> 9)] + pre[node];
    }
    __syncthreads();
    const int2* d2p = reinterpret_cast<const int2*>(ep.dst[rel]) + (size_t)chunk * CH2;
    const int2* s2p = reinterpret_cast<const int2*>(ep.src[rel]) + (size_t)chunk * CH2;
    const float* cf = coef + rel * NB;
    int2* epk = epack + (size_t)rel * EB;
    for (int i = threadIdx.x; i < CH2; i += 256) {
        int2 d2 = d2p[i];
        int2 s2 = s2p[i];
        int n0 = d2.x - lo;
        if ((unsigned)n0 < (unsigned)FR) {
            int pos = atomicAdd(&cur[n0], 1);
            epk[pos] = make_int2(s2.x, __float_as_int(cf[s2.x]));
        }
        int n1 = d2.y - lo;
        if ((unsigned)n1 < (unsigned)FR) {
            int pos = atomicAdd(&cur[n1], 1);
            epk[pos] = make_int2(s2.y, __float_as_int(cf[s2.y]));
        }
    }
}

#define FMA8A(c, rv, A)                                                        \
    {                                                                          \
        A[0] = fmaf(hlo(rv.x), c, A[0]); A[1] = fmaf(hhi(rv.x), c, A[1]);      \
        A[2] = fmaf(hlo(rv.y), c, A[2]); A[3] = fmaf(hhi(rv.y), c, A[3]);      \
        A[4] = fmaf(hlo(rv.z), c, A[4]); A[5] = fmaf(hhi(rv.z), c, A[5]);      \
        A[6] = fmaf(hlo(rv.w), c, A[6]); A[7] = fmaf(hhi(rv.w), c, A[7]);      \
    }

// Range-sorted barrier-free gather. Block = 64 dst rows x ONE relation
// (blockIdx.y: t = y>>1, h = y&1). Edges sorted by (row, range) in LDS;
// each group then iterates its rows' full sorted segments pipelined — the
// sort alone provides range locality, no pass barriers or run tables.
__global__ __launch_bounds__(256, 8) void k_gather(
    const unsigned short* __restrict__ xh,  // [2][NB][D] fp16: drug then dis
    const int* __restrict__ offs, const int* __restrict__ chunksum,
    const int2* __restrict__ epack,
    unsigned short* __restrict__ agg) {     // [2*NB][256] fp16 (aliases d_out)
    __shared__ int2 ebuf[CAP];              // 8 KB (sorted)
    __shared__ unsigned short key[CAP];     // 2 KB (row*NRGP+range per edge)
    __shared__ int soff[65];
    __shared__ int cnt[64 * NRGP];          // counts -> scatter cursors
    const int t = blockIdx.y >> 1, h = blockIdx.y & 1;
    const int rel = h ? (2 + t) : t;
    const int row0 = blockIdx.x * 64;
    const int tid = threadIdx.x;
    const int g = tid >> 4, l16 = tid & 15;
    const int cbase = l16 * 8;              // this lane's 8 fp16 columns
    const unsigned short* x = xh + (size_t)(rel >= 2 ? NB * D : 0);
    const int2* epk = epack + (size_t)rel * EB;

    if (tid < 65) {
        int idx = row0 + tid;
        soff[tid] = (idx < NB)
            ? offs[rel * (NB + 1) + idx] + chunksum[rel * NCH + (idx >> 9)]
            : EB;
    }
    for (int i = tid; i < 64 * NRGP; i += 256) cnt[i] = 0;
    __syncthreads();

    const int base = soff[0];
    const int tot0 = soff[64] - base;
    const int tot = tot0 < CAP ? tot0 : CAP;

    // pass A: count (row, range); row via binary search over soff
    for (int i = tid; i < tot; i += 256) {
        int2 e = epk[base + i];
        int rng = (int)((unsigned)e.x / RQ);
        int lo = 0, hi = 64;
        while (hi - lo > 1) {
            int mid = (lo + hi) >> 1;
            if (soff[mid] - base <= i) lo = mid; else hi = mid;
        }
        int k = lo * NRGP + rng;
        key[i] = (unsigned short)k;
        atomicAdd(&cnt[k], 1);
    }
    __syncthreads();

    // per-row exclusive prefix over ranges -> scatter cursors
    if (tid < 64) {
        int run = soff[tid] - base; if (run > CAP) run = CAP;
        for (int r = 0; r < NRGP; ++r) {
            int c = cnt[tid * NRGP + r];
            cnt[tid * NRGP + r] = run;
            run += c;
        }
    }
    __syncthreads();

    // pass B: scatter into sorted order (re-read epk; L2-hot)
    for (int i = tid; i < tot; i += 256) {
        int2 e = epk[base + i];
        int pos = atomicAdd(&cnt[key[i]], 1);
        ebuf[pos] = e;
    }
    __syncthreads();

    float racc[4][8] = {};

    // ---- per-row sorted-segment pipelined gather (no barriers) ----
#pragma unroll
    for (int rr = 0; rr < 4; ++rr) {
        int glo = soff[g * 4 + rr] - base;
        int ghi0 = soff[g * 4 + rr + 1] - base;
        int s = glo < CAP ? glo : CAP;
        int e_ = ghi0 < CAP ? ghi0 : CAP;
        if (s < e_) {
            int2 e0 = ebuf[s];
            float c0 = __int_as_float(e0.y);
            uint4 rv0 = *reinterpret_cast<const uint4*>(
                x + ((unsigned)e0.x * D + cbase));
            for (int i = s + 1; i < e_; ++i) {
                int2 e1 = ebuf[i];
                float c1 = __int_as_float(e1.y);
                uint4 rv1 = *reinterpret_cast<const uint4*>(
                    x + ((unsigned)e1.x * D + cbase));
                FMA8A(c0, rv0, racc[rr]);
                c0 = c1; rv0 = rv1;
            }
            FMA8A(c0, rv0, racc[rr]);
        }
        // rare overflow tail (window beyond CAP) straight from global
        int st = glo > CAP ? glo : CAP;
        for (int i = st; i < ghi0; ++i) {
            int2 e = epk[base + i];
            float c = __int_as_float(e.y);
            uint4 rv = *reinterpret_cast<const uint4*>(
                x + ((unsigned)e.x * D + cbase));
            FMA8A(c, rv, racc[rr]);
        }
        // scale + store fp16 half-row (256B contiguous per row per half)
        int row = row0 + g * 4 + rr;
        if (row < NB) {
            int dg = ghi0 - glo;
            float di = rsqrtf((float)(dg > 1 ? dg : 1));
            unsigned q[4];
#pragma unroll
            for (int k2 = 0; k2 < 4; ++k2) {
                unsigned lo2 = __half_as_ushort(__float2half(racc[rr][2 * k2] * di));
                unsigned hi2 = __half_as_ushort(__float2half(racc[rr][2 * k2 + 1] * di));
                q[k2] = lo2 | (hi2 << 16);
            }
            *reinterpret_cast<uint4*>(
                agg + ((size_t)(t * NB + row) * 256 + h * 128 + cbase)) =
                make_uint4(q[0], q[1], q[2], q[3]);
        }
    }
}

// Dense MFMA GEMM: out[r][j] = prelu(sum_k agg[r][k] * Wcat_t[k][j] + bias).
__global__ __launch_bounds__(256) void k_gemm(
    const _Float16* agg,                    // aliases out
    const _Float16* __restrict__ Wb,
    const float* __restrict__ b, const float* __restrict__ prelu_a,
    float* out) {
    const int t = blockIdx.y;
    const int tid = threadIdx.x, w = tid >> 6, l = tid & 63;
    const int rbase = t * NB + blockIdx.x * 64 + w * 16;
    const int rmax = t * NB + NB - 1;
    const int lk = (l >> 4) * 8;
    f32x4 acc[8] = {};
    const f16x8* wb = reinterpret_cast<const f16x8*>(Wb + (size_t)t * 32768);
    int ra = rbase + (l & 15); if (ra > rmax) ra = rmax;
    const _Float16* ap = agg + (size_t)ra * 256 + lk;
#pragma unroll
    for (int ks = 0; ks < 8; ++ks) {
        f16x8 a = *reinterpret_cast<const f16x8*>(ap + ks * 32);
#pragma unroll
        for (int jt = 0; jt < 8; ++jt) {
            f16x8 bf = wb[(jt * 8 + ks) * 64 + l];
            acc[jt] = __builtin_amdgcn_mfma_f32_16x16x32_f16(a, bf, acc[jt], 0, 0, 0);
        }
    }
    float pa = prelu_a[0];
    const int rowoff = (l >> 4) * 4;
#pragma unroll
    for (int jt = 0; jt < 8; ++jt) {
        int col = jt * 16 + (l & 15);
        float bs = b[t * D + col] + b[(2 + t) * D + col];
#pragma unroll
        for (int m = 0; m < 4; ++m) {
            int grow = rbase + rowoff + m;
            if (grow <= rmax) {
                float v = acc[jt][m] + bs;
                v = v >= 0.f ? v : pa * v;
                out[(size_t)grow * D + col] = v;
            }
        }
    }
}

extern "C" void kernel_launch(void* const* d_in, const int* in_sizes, int n_in,
                              void* d_out, int out_size, void* d_ws, size_t ws_size,
                              hipStream_t stream) {
    const float* x_drug = (const float*)d_in[0];
    const float* x_dis  = (const float*)d_in[1];
    const float* W      = (const float*)d_in[2];   // [4,128,128]
    const float* b      = (const float*)d_in[3];   // [4,128]
    const float* pa     = (const float*)d_in[4];   // [1]
    EdgePtrs ep;
    ep.src[0] = (const int*)d_in[5];  ep.dst[0] = (const int*)d_in[6];   // dd
    ep.src[1] = (const int*)d_in[7];  ep.dst[1] = (const int*)d_in[8];   // ds
    ep.src[2] = (const int*)d_in[9];  ep.dst[2] = (const int*)d_in[10];  // sd
    ep.src[3] = (const int*)d_in[11]; ep.dst[3] = (const int*)d_in[12];  // ss

    // workspace layout (bytes); no memset needed — all buffers fully written
    char* ws = (char*)d_ws;
    unsigned short* cnt2in = (unsigned short*)(ws + 0);         // [4][16][NB]
    unsigned short* cnt2o  = (unsigned short*)(ws + 6400000);   // [4][16][NB]
    float* coef     = (float*)(ws + 12800000);  // [4][NB]
    int*   offs     = (int*)(ws + 13600000);    // [4][NB+1]
    int*   chunksum = (int*)(ws + 14400064);    // [4][NCH]
    int*   done     = (int*)(ws + 14401632);    // 1 int (scan counter)
    int2*  epack    = (int2*)(ws + 14401664);   // [4][EB] int2 (16 MB)
    unsigned short* xh = (unsigned short*)(ws + 30401664);  // fp16 x (25.6 MB)
    _Float16* Wb    = (_Float16*)(ws + 56001664); // 128 KB packed W
    // total ~56.1 MB

    k_cvt<<<12532, 256, 0, stream>>>(x_drug, x_dis, xh, W, Wb, done);
    k_hist8<<<dim3(NCHK, 8), 256, 0, stream>>>(ep, cnt2in, cnt2o);
    k_scan1<<<dim3(NCH, 4), 512, 0, stream>>>(cnt2in, cnt2o, coef, offs,
                                              chunksum, done);
    k_fill3<<<dim3(NCHK, NRG, 4), 256, 0, stream>>>(
        ep, cnt2in, coef, offs, chunksum, epack);
    k_gather<<<dim3(782, 4), 256, 0, stream>>>(
        xh, offs, chunksum, epack, (unsigned short*)d_out);
    k_gemm<<<dim3(782, 2), 256, 0, stream>>>(
        (const _Float16*)d_out, Wb, b, pa, (float*)d_out);
}

// Round 23
// 217.944 us; speedup vs baseline: 1.2556x; 1.2556x over previous
//
#include <hip/hip_runtime.h>
#include <hip/hip_fp16.h>

// Node_Embedding: HeteroGraphConv(sum) of 4 GraphConv relations + PReLU.
// FINAL (best verified, R18 = 217.7us; 870us naive -> 4.0x):
//   k_cvt (x->fp16 + W-pack) ; k_hist (chunk x range LDS u16 histograms) ;
//   k_scan1..3 (chunk-prefix + CSR offs + coef) ; k_fill3 (chunked LDS-cursor
//   counting sort, int2 (src,coef)) ; k_gather (src-range-blocked gather,
//   edges in-block sorted by (row, range) -> pipelined run iteration, 4 range
//   passes w/ block barrier) ; k_gemm (MFMA f16 + bias + PReLU).
// Validated mechanisms: range-blocking cut L2-miss traffic 372->147MB and
// killed 9x write amplification (R15); sorted runs + 4 passes + 1-deep load
// pipeline: gather 130->77us (R16-R18). Refuted alternatives: fused
// gather+GEMM (occupancy, R19), barrier-free gather (locality, R22),
// completion-counter scan fold (coherence stall, R22).

#define NB 50000   // nodes per type
#define EB 500000  // edges per relation
#define D  128
#define NCH 98     // ceil(NB/512)
#define CAP 1024   // gather LDS edge capacity (mean 640 per 64 rows)
#define NCHK 16    // edge chunks (CSR build)
#define CH2 15625  // (EB/NCHK)/2 int2 loads per chunk
#define NRG 4      // node ranges (CSR build)
#define FR 12500   // nodes per range (CSR build)
#define NRGP 4     // gather src-range passes
#define RQ 12500   // NB/NRGP

struct EdgePtrs { const int* src[4]; const int* dst[4]; };

typedef _Float16 f16x8 __attribute__((ext_vector_type(8)));
typedef float f32x4 __attribute__((ext_vector_type(4)));

__device__ inline float hlo(unsigned u) {
    return __half2float(__ushort_as_half((unsigned short)(u & 0xffffu)));
}
__device__ inline float hhi(unsigned u) {
    return __half2float(__ushort_as_half((unsigned short)(u >> 16)));
}

// x (fp32) -> fp16, float4/thread; last 32 blocks pack W into MFMA B-frags.
__global__ __launch_bounds__(256) void k_cvt(const float* __restrict__ xd,
                                             const float* __restrict__ xs,
                                             unsigned short* __restrict__ xh,
                                             const float* __restrict__ W,
                                             _Float16* __restrict__ Wb) {
    int bx = blockIdx.x;
    if (bx < 12500) {
        int i = bx * 256 + threadIdx.x;   // float4 index, 3.2M total
        const int half = NB * D / 4;
        const float* src = (i < half) ? xd : xs;
        int j = (i < half) ? i : i - half;
        float4 v = reinterpret_cast<const float4*>(src)[j];
        ushort4 o;
        o.x = __half_as_ushort(__float2half(v.x));
        o.y = __half_as_ushort(__float2half(v.y));
        o.z = __half_as_ushort(__float2half(v.z));
        o.w = __half_as_ushort(__float2half(v.w));
        reinterpret_cast<ushort4*>(xh)[i] = o;
    } else {
        int idx = (bx - 12500) * 256 + threadIdx.x;   // 8192 total
        int t = idx >> 12, jt = (idx >> 9) & 7, ks = (idx >> 6) & 7, l = idx & 63;
        int col = jt * 16 + (l & 15);
        int kb = ks * 32 + (l >> 4) * 8;
        _Float16 h[8];
#pragma unroll
        for (int m = 0; m < 8; ++m) {
            int k = kb + m;
            int r = (k < 128) ? t : (2 + t);
            h[m] = (_Float16)W[r * D * D + (k & 127) * D + col];
        }
        *reinterpret_cast<f16x8*>(Wb + (size_t)idx * 8) = *reinterpret_cast<f16x8*>(h);
    }
}

// Chunked LDS histogram. Block (chunk, range, z) with z = io*4 + rel.
__global__ __launch_bounds__(256) void k_hist(EdgePtrs ep,
                                              unsigned short* __restrict__ cnt2in,
                                              unsigned short* __restrict__ cnt2o) {
    __shared__ unsigned pk[FR / 2];   // packed u16 pairs, 25 KB
    const int chunk = blockIdx.x, range = blockIdx.y;
    const int rel = blockIdx.z & 3, io = blockIdx.z >> 2;
    const int lo = range * FR;
    const int* arr = io ? ep.src[rel] : ep.dst[rel];
    for (int i = threadIdx.x; i < FR / 2; i += 256) pk[i] = 0;
    __syncthreads();
    const int2* a2 = reinterpret_cast<const int2*>(arr) + (size_t)chunk * CH2;
    for (int i = threadIdx.x; i < CH2; i += 256) {
        int2 v = a2[i];
        int n0 = v.x - lo;
        if ((unsigned)n0 < (unsigned)FR) atomicAdd(&pk[n0 >> 1], 1u << (16 * (n0 & 1)));
        int n1 = v.y - lo;
        if ((unsigned)n1 < (unsigned)FR) atomicAdd(&pk[n1 >> 1], 1u << (16 * (n1 & 1)));
    }
    __syncthreads();
    unsigned short* out = io ? cnt2o : cnt2in;
    unsigned* dst = reinterpret_cast<unsigned*>(out + ((size_t)(rel * NCHK + chunk)) * NB);
    for (int i = threadIdx.x; i < FR / 2; i += 256) dst[lo / 2 + i] = pk[i];
}

// Phase 1: per node — chunk-prefix cnt2in in place (u16), outdeg -> coef,
// then per-512-node exclusive block scan of total in-degree.
__global__ __launch_bounds__(512) void k_scan1(unsigned short* __restrict__ cnt2in,
                                               const unsigned short* __restrict__ cnt2o,
                                               float* __restrict__ coef,
                                               int* __restrict__ offs,
                                               int* __restrict__ chunksum) {
    int r = blockIdx.y, c = blockIdx.x, t = threadIdx.x;
    int node = c * 512 + t;
    int v = 0;
    if (node < NB) {
        int tin = 0;
#pragma unroll
        for (int k = 0; k < NCHK; ++k) {
            size_t idx = ((size_t)(r * NCHK + k)) * NB + node;
            int cc = cnt2in[idx];
            cnt2in[idx] = (unsigned short)tin;   // exclusive chunk prefix
            tin += cc;
        }
        v = tin;
        int tout = 0;
#pragma unroll
        for (int k = 0; k < NCHK; ++k)
            tout += cnt2o[((size_t)(r * NCHK + k)) * NB + node];
        coef[r * NB + node] = rsqrtf((float)(tout > 1 ? tout : 1));
    }
    __shared__ int sh[512];
    sh[t] = v;
    __syncthreads();
    for (int off = 1; off < 512; off <<= 1) {
        int u = (t >= off) ? sh[t - off] : 0;
        __syncthreads();
        sh[t] += u;
        __syncthreads();
    }
    int incl = sh[t];
    if (node < NB) offs[r * (NB + 1) + node] = incl - v;  // local exclusive
    if (t == 511) chunksum[r * NCH + c] = incl;
}

// Phase 2: exclusive scan of the NCH chunk totals per relation (wave r).
__global__ __launch_bounds__(256) void k_scan2(int* __restrict__ chunksum) {
    int r = threadIdx.x >> 6, lane = threadIdx.x & 63;
    int* cs = chunksum + r * NCH;
    int s0 = cs[lane];
    int s1 = (64 + lane < NCH) ? cs[64 + lane] : 0;
    int x = s0;
    for (int d = 1; d < 64; d <<= 1) { int u = __shfl_up(x, d, 64); if (lane >= d) x += u; }
    int tot0 = __shfl(x, 63, 64);
    int y = s1;
    for (int d = 1; d < 64; d <<= 1) { int u = __shfl_up(y, d, 64); if (lane >= d) y += u; }
    y += tot0;
    cs[lane] = x - s0;
    if (64 + lane < NCH) cs[64 + lane] = y - s1;
}

// Phase 3: add chunk base; offs[NB] = EB.
__global__ __launch_bounds__(512) void k_scan3(int* __restrict__ offs,
                                               const int* __restrict__ chunksum) {
    int r = blockIdx.y, c = blockIdx.x, t = threadIdx.x;
    int node = c * 512 + t;
    if (node < NB)
        offs[r * (NB + 1) + node] += chunksum[r * NCH + c];
    if (c == NCH - 1 && t == 0) offs[r * (NB + 1) + NB] = EB;
}

// Chunked counting-sort placement: int2 (src, coef) payload.
__global__ __launch_bounds__(256) void k_fill3(EdgePtrs ep,
                                               const unsigned short* __restrict__ cnt2in,
                                               const float* __restrict__ coef,
                                               const int* __restrict__ offs,
                                               int2* __restrict__ epack) {
    __shared__ int cur[FR];           // 50 KB
    const int chunk = blockIdx.x, range = blockIdx.y, rel = blockIdx.z;
    const int lo = range * FR;
    const unsigned short* pre = cnt2in + ((size_t)(rel * NCHK + chunk)) * NB;
    for (int i = threadIdx.x; i < FR; i += 256)
        cur[i] = offs[rel * (NB + 1) + lo + i] + pre[lo + i];
    __syncthreads();
    const int2* d2p = reinterpret_cast<const int2*>(ep.dst[rel]) + (size_t)chunk * CH2;
    const int2* s2p = reinterpret_cast<const int2*>(ep.src[rel]) + (size_t)chunk * CH2;
    const float* cf = coef + rel * NB;
    int2* epk = epack + (size_t)rel * EB;
    for (int i = threadIdx.x; i < CH2; i += 256) {
        int2 d2 = d2p[i];
        int2 s2 = s2p[i];
        int n0 = d2.x - lo;
        if ((unsigned)n0 < (unsigned)FR) {
            int pos = atomicAdd(&cur[n0], 1);
            epk[pos] = make_int2(s2.x, __float_as_int(cf[s2.x]));
        }
        int n1 = d2.y - lo;
        if ((unsigned)n1 < (unsigned)FR) {
            int pos = atomicAdd(&cur[n1], 1);
            epk[pos] = make_int2(s2.y, __float_as_int(cf[s2.y]));
        }
    }
}

#define FMA8A(c, rv, A)                                                        \
    {                                                                          \
        A[0] = fmaf(hlo(rv.x), c, A[0]); A[1] = fmaf(hhi(rv.x), c, A[1]);      \
        A[2] = fmaf(hlo(rv.y), c, A[2]); A[3] = fmaf(hhi(rv.y), c, A[3]);      \
        A[4] = fmaf(hlo(rv.z), c, A[4]); A[5] = fmaf(hhi(rv.z), c, A[5]);      \
        A[6] = fmaf(hlo(rv.w), c, A[6]); A[7] = fmaf(hhi(rv.w), c, A[7]);      \
    }

// Src-range-blocked gather, edges in-block sorted by (row, range).
// Block = 64 dst rows x ONE relation (blockIdx.y: t = y>>1, h = y&1).
// Staging: count (row,range) -> per-row run table -> scatter sorted.
// Pass loop: pipelined iteration over each row's range-r run (load edge i+1
// before FMAs of edge i), barrier per pass (keeps slab set L2-resident).
__global__ __launch_bounds__(256, 8) void k_gather(
    const unsigned short* __restrict__ xh,  // [2][NB][D] fp16: drug then dis
    const int* __restrict__ offs, const int2* __restrict__ epack,
    unsigned short* __restrict__ agg) {     // [2*NB][256] fp16 (aliases d_out)
    __shared__ int2 ebuf[CAP];              // 8 KB (sorted)
    __shared__ unsigned short key[CAP];     // 2 KB (row*NRGP+range per edge)
    __shared__ int soff[65];
    __shared__ int cnt[64 * NRGP];          // counts -> scatter cursors
    __shared__ int runstart[64 * (NRGP + 1)]; // run boundaries
    const int t = blockIdx.y >> 1, h = blockIdx.y & 1;
    const int rel = h ? (2 + t) : t;
    const int row0 = blockIdx.x * 64;
    const int tid = threadIdx.x;
    const int g = tid >> 4, l16 = tid & 15;
    const int cbase = l16 * 8;              // this lane's 8 fp16 columns
    const unsigned short* x = xh + (size_t)(rel >= 2 ? NB * D : 0);
    const int2* epk = epack + (size_t)rel * EB;

    if (tid < 65) {
        int idx = row0 + tid; if (idx > NB) idx = NB;
        soff[tid] = offs[rel * (NB + 1) + idx];
    }
    for (int i = tid; i < 64 * NRGP; i += 256) cnt[i] = 0;
    __syncthreads();

    const int base = soff[0];
    const int tot0 = soff[64] - base;
    const int tot = tot0 < CAP ? tot0 : CAP;

    // pass A: count (row, range); row via binary search over soff
    for (int i = tid; i < tot; i += 256) {
        int2 e = epk[base + i];
        int rng = (int)((unsigned)e.x / RQ);
        int lo = 0, hi = 64;
        while (hi - lo > 1) {
            int mid = (lo + hi) >> 1;
            if (soff[mid] - base <= i) lo = mid; else hi = mid;
        }
        int k = lo * NRGP + rng;
        key[i] = (unsigned short)k;
        atomicAdd(&cnt[k], 1);
    }
    __syncthreads();

    // per-row exclusive prefix over ranges -> run table + scatter cursors
    if (tid < 64) {
        int run = soff[tid] - base; if (run > CAP) run = CAP;
        for (int r = 0; r < NRGP; ++r) {
            int c = cnt[tid * NRGP + r];
            runstart[tid * (NRGP + 1) + r] = run;
            cnt[tid * NRGP + r] = run;
            run += c;
        }
        runstart[tid * (NRGP + 1) + NRGP] = run;
    }
    __syncthreads();

    // pass B: scatter into sorted order (re-read epk; L2-hot)
    for (int i = tid; i < tot; i += 256) {
        int2 e = epk[base + i];
        int pos = atomicAdd(&cnt[key[i]], 1);
        ebuf[pos] = e;
    }
    __syncthreads();

    // per-row segment bounds (group-uniform)
    int glo[4], ghi0[4];
    float dinv[4];
#pragma unroll
    for (int rr = 0; rr < 4; ++rr) {
        glo[rr]  = soff[g * 4 + rr] - base;
        ghi0[rr] = soff[g * 4 + rr + 1] - base;
        int dg = ghi0[rr] - glo[rr];
        dinv[rr] = rsqrtf((float)(dg > 1 ? dg : 1));
    }

    float racc[4][8] = {};

    // ---- range passes: pipelined run iteration ----
    for (int r = 0; r < NRGP; ++r) {
#pragma unroll
        for (int rr = 0; rr < 4; ++rr) {
            int row = g * 4 + rr;
            int s = runstart[row * (NRGP + 1) + r];
            int e_ = runstart[row * (NRGP + 1) + r + 1];
            if (s < e_) {
                int2 e0 = ebuf[s];
                float c0 = __int_as_float(e0.y);
                uint4 rv0 = *reinterpret_cast<const uint4*>(
                    x + ((unsigned)e0.x * D + cbase));
                for (int i = s + 1; i < e_; ++i) {
                    int2 e1 = ebuf[i];
                    float c1 = __int_as_float(e1.y);
                    uint4 rv1 = *reinterpret_cast<const uint4*>(
                        x + ((unsigned)e1.x * D + cbase));
                    FMA8A(c0, rv0, racc[rr]);
                    c0 = c1; rv0 = rv1;
                }
                FMA8A(c0, rv0, racc[rr]);
            }
        }
        __syncthreads();
    }

    // rare overflow tail (window beyond CAP) straight from global, unsorted
#pragma unroll
    for (int rr = 0; rr < 4; ++rr) {
        int st = glo[rr] > CAP ? glo[rr] : CAP;
        for (int i = st; i < ghi0[rr]; ++i) {
            int2 e = epk[base + i];
            float c = __int_as_float(e.y);
            uint4 rv = *reinterpret_cast<const uint4*>(
                x + ((unsigned)e.x * D + cbase));
            FMA8A(c, rv, racc[rr]);
        }
    }

    // scale + store fp16 half-rows (256B contiguous per row per block-half)
#pragma unroll
    for (int rr = 0; rr < 4; ++rr) {
        int row = row0 + g * 4 + rr;
        if (row < NB) {
            float di = dinv[rr];
            unsigned q[4];
#pragma unroll
            for (int k2 = 0; k2 < 4; ++k2) {
                unsigned lo2 = __half_as_ushort(__float2half(racc[rr][2 * k2] * di));
                unsigned hi2 = __half_as_ushort(__float2half(racc[rr][2 * k2 + 1] * di));
                q[k2] = lo2 | (hi2 << 16);
            }
            *reinterpret_cast<uint4*>(
                agg + ((size_t)(t * NB + row) * 256 + h * 128 + cbase)) =
                make_uint4(q[0], q[1], q[2], q[3]);
        }
    }
}

// Dense MFMA GEMM: out[r][j] = prelu(sum_k agg[r][k] * Wcat_t[k][j] + bias).
__global__ __launch_bounds__(256) void k_gemm(
    const _Float16* agg,                    // aliases out
    const _Float16* __restrict__ Wb,
    const float* __restrict__ b, const float* __restrict__ prelu_a,
    float* out) {
    const int t = blockIdx.y;
    const int tid = threadIdx.x, w = tid >> 6, l = tid & 63;
    const int rbase = t * NB + blockIdx.x * 64 + w * 16;
    const int rmax = t * NB + NB - 1;
    const int lk = (l >> 4) * 8;
    f32x4 acc[8] = {};
    const f16x8* wb = reinterpret_cast<const f16x8*>(Wb + (size_t)t * 32768);
    int ra = rbase + (l & 15); if (ra > rmax) ra = rmax;
    const _Float16* ap = agg + (size_t)ra * 256 + lk;
#pragma unroll
    for (int ks = 0; ks < 8; ++ks) {
        f16x8 a = *reinterpret_cast<const f16x8*>(ap + ks * 32);
#pragma unroll
        for (int jt = 0; jt < 8; ++jt) {
            f16x8 bf = wb[(jt * 8 + ks) * 64 + l];
            acc[jt] = __builtin_amdgcn_mfma_f32_16x16x32_f16(a, bf, acc[jt], 0, 0, 0);
        }
    }
    float pa = prelu_a[0];
    const int rowoff = (l >> 4) * 4;
#pragma unroll
    for (int jt = 0; jt < 8; ++jt) {
        int col = jt * 16 + (l & 15);
        float bs = b[t * D + col] + b[(2 + t) * D + col];
#pragma unroll
        for (int m = 0; m < 4; ++m) {
            int grow = rbase + rowoff + m;
            if (grow <= rmax) {
                float v = acc[jt][m] + bs;
                v = v >= 0.f ? v : pa * v;
                out[(size_t)grow * D + col] = v;
            }
        }
    }
}

extern "C" void kernel_launch(void* const* d_in, const int* in_sizes, int n_in,
                              void* d_out, int out_size, void* d_ws, size_t ws_size,
                              hipStream_t stream) {
    const float* x_drug = (const float*)d_in[0];
    const float* x_dis  = (const float*)d_in[1];
    const float* W      = (const float*)d_in[2];   // [4,128,128]
    const float* b      = (const float*)d_in[3];   // [4,128]
    const float* pa     = (const float*)d_in[4];   // [1]
    EdgePtrs ep;
    ep.src[0] = (const int*)d_in[5];  ep.dst[0] = (const int*)d_in[6];   // dd
    ep.src[1] = (const int*)d_in[7];  ep.dst[1] = (const int*)d_in[8];   // ds
    ep.src[2] = (const int*)d_in[9];  ep.dst[2] = (const int*)d_in[10];  // sd
    ep.src[3] = (const int*)d_in[11]; ep.dst[3] = (const int*)d_in[12];  // ss

    // workspace layout (bytes); no memset needed — all buffers fully written
    char* ws = (char*)d_ws;
    unsigned short* cnt2in = (unsigned short*)(ws + 0);         // [4][16][NB]
    unsigned short* cnt2o  = (unsigned short*)(ws + 6400000);   // [4][16][NB]
    float* coef     = (float*)(ws + 12800000);  // [4][NB]
    int*   offs     = (int*)(ws + 13600000);    // [4][NB+1]
    int*   chunksum = (int*)(ws + 14400064);    // [4][NCH]
    int2*  epack    = (int2*)(ws + 14401664);   // [4][EB] int2 (16 MB)
    unsigned short* xh = (unsigned short*)(ws + 30401664);  // fp16 x (25.6 MB)
    _Float16* Wb    = (_Float16*)(ws + 56001664); // 128 KB packed W
    // total ~56.1 MB

    k_cvt<<<12532, 256, 0, stream>>>(x_drug, x_dis, xh, W, Wb);
    k_hist<<<dim3(NCHK, NRG, 8), 256, 0, stream>>>(ep, cnt2in, cnt2o);
    k_scan1<<<dim3(NCH, 4), 512, 0, stream>>>(cnt2in, cnt2o, coef, offs, chunksum);
    k_scan2<<<1, 256, 0, stream>>>(chunksum);
    k_scan3<<<dim3(NCH, 4), 512, 0, stream>>>(offs, chunksum);
    k_fill3<<<dim3(NCHK, NRG, 4), 256, 0, stream>>>(ep, cnt2in, coef, offs, epack);
    k_gather<<<dim3(782, 4), 256, 0, stream>>>(
        xh, offs, epack, (unsigned short*)d_out);
    k_gemm<<<dim3(782, 2), 256, 0, stream>>>(
        (const _Float16*)d_out, Wb, b, pa, (float*)d_out);
}